// Round 11
// baseline (241.473 us; speedup 1.0000x reference)
//
#include <hip/hip_runtime.h>
#include <math.h>

// FeatureSpecExtractor: per-(b,f) EMA-normalize over time.
//   s_t = 0.95*s_{t-1} + 0.05*|x_t|;  y_t = x_t / sqrt(s_t)
// spec: (16,1,257,8000) f32, features 0..255. out: (16,1,256,8000) f32.
//
// v4: barrier-free streaming wave-scan. One WAVE per row; 31 iters of
// 256 floats (1 float4/lane, coalesced) + 64-float tail (1 float/lane).
// Intra-wave weighted Kogge-Stone scan (6 shuffles, no LDS/barriers);
// EMA state carried serially in a register (carry fma, 0.95^256 = 2e-6).
// Register double-buffer prefetch keeps loads in flight continuously --
// attacks the phase-lockstep memory idle seen in v2/v3 (2.4 TB/s eff
// with VALUBusy 21%, nothing saturated).

#define TLEN    8000
#define NITER   31            // full 256-float wave-iterations
#define TAILOFF 7936          // NITER*256; tail = 64 floats
#define ALPHA   0.95f
#define OMA     0.05f

// powers of 0.95 (A4 = 0.95^4 for the float4-chunk scan; A1 for the tail)
#define A4_1   0.81450625f    // 0.95^4
#define A4_2   0.66342043f    // 0.95^8
#define A4_4   0.44012667f    // 0.95^16
#define A4_8   0.19371149f    // 0.95^32
#define A4_16  0.03752414f    // 0.95^64
#define A4_32  0.00140806f    // 0.95^128
#define A256   1.98263565e-06f// 0.95^256 (carry factor per iteration)
#define A1_1   0.95f
#define A1_2   0.9025f
#define A1_4   0.81450625f
#define A1_8   0.66342043f
#define A1_16  0.44012667f
#define A1_32  0.19371149f
#define LOG2_A1 (-0.07400058f) // log2(0.95)
#define LOG2_A4 (-0.29600231f) // 4*log2(0.95)

__global__ __launch_bounds__(256) void fse_kernel(
    const float* __restrict__ spec,
    const float* __restrict__ uns,
    float* __restrict__ out)
{
    const int tid  = threadIdx.x;
    const int lane = tid & 63;
    const int wv   = tid >> 6;                 // wave in block: 0..3
    const int bf   = blockIdx.x * 4 + wv;      // row id 0..4095
    const int b    = bf >> 8;
    const int f    = bf & 255;

    const float*  inrow  = spec + ((size_t)b * 257 + (size_t)f) * TLEN;
    float*        outrow = out  + ((size_t)bf) * TLEN;
    const float4* pin  = (const float4*)inrow;
    float4*       pout = (float4*)outrow;

    const float pl4 = exp2f(LOG2_A4 * (float)lane);  // 0.95^(4*lane)
    float carry = uns[f];                            // EMA state before next iter

    // register double-buffer prefetch, depth 2
    float4 P0 = pin[lane];
    float4 P1 = pin[64 + lane];

#pragma unroll 2
    for (int i = 0; i < NITER; ++i) {
        float4 x = (i & 1) ? P1 : P0;
        if (i + 2 < NITER) {                         // uniform branch
            float4 nf = pin[(i + 2) * 64 + lane];
            if (i & 1) P1 = nf; else P0 = nf;        // static after unroll-2
        }

        // local chunk scan (zero-seed): d = sum 0.95^(3-j) * 0.05*|x_j|
        float d;
        d = OMA * fabsf(x.x);
        d = fmaf(fabsf(x.y), OMA, d * ALPHA);
        d = fmaf(fabsf(x.z), OMA, d * ALPHA);
        d = fmaf(fabsf(x.w), OMA, d * ALPHA);

        // intra-wave weighted Kogge-Stone (inclusive, zero-seed)
        float v = d, t;
        t = __shfl_up(v, 1);  if (lane >= 1)  v = fmaf(A4_1,  t, v);
        t = __shfl_up(v, 2);  if (lane >= 2)  v = fmaf(A4_2,  t, v);
        t = __shfl_up(v, 4);  if (lane >= 4)  v = fmaf(A4_4,  t, v);
        t = __shfl_up(v, 8);  if (lane >= 8)  v = fmaf(A4_8,  t, v);
        t = __shfl_up(v, 16); if (lane >= 16) v = fmaf(A4_16, t, v);
        t = __shfl_up(v, 32); if (lane >= 32) v = fmaf(A4_32, t, v);

        // per-lane incoming state: A4^lane * carry + (data exclusive)
        float e = __shfl_up(v, 1);
        if (lane == 0) e = 0.0f;
        float s = fmaf(pl4, carry, e);

        // serial carry to next iteration (1 broadcast + 1 fma)
        float incl63 = __shfl(v, 63);
        carry = fmaf(A256, carry, incl63);

        // exact 4-step recurrence + normalize
        s = fmaf(fabsf(x.x), OMA, s * ALPHA); x.x *= rsqrtf(s);
        s = fmaf(fabsf(x.y), OMA, s * ALPHA); x.y *= rsqrtf(s);
        s = fmaf(fabsf(x.z), OMA, s * ALPHA); x.z *= rsqrtf(s);
        s = fmaf(fabsf(x.w), OMA, s * ALPHA); x.w *= rsqrtf(s);

        pout[i * 64 + lane] = x;
    }

    // ---- tail: 64 floats, 1 per lane ----
    {
        float xt = inrow[TAILOFF + lane];
        float v = OMA * fabsf(xt), t;
        t = __shfl_up(v, 1);  if (lane >= 1)  v = fmaf(A1_1,  t, v);
        t = __shfl_up(v, 2);  if (lane >= 2)  v = fmaf(A1_2,  t, v);
        t = __shfl_up(v, 4);  if (lane >= 4)  v = fmaf(A1_4,  t, v);
        t = __shfl_up(v, 8);  if (lane >= 8)  v = fmaf(A1_8,  t, v);
        t = __shfl_up(v, 16); if (lane >= 16) v = fmaf(A1_16, t, v);
        t = __shfl_up(v, 32); if (lane >= 32) v = fmaf(A1_32, t, v);

        float e = __shfl_up(v, 1);
        if (lane == 0) e = 0.0f;
        const float pl1 = exp2f(LOG2_A1 * (float)lane);  // 0.95^lane
        float s = fmaf(pl1, carry, e);                   // state before own elem
        s = fmaf(fabsf(xt), OMA, s * ALPHA);
        outrow[TAILOFF + lane] = xt * rsqrtf(s);
    }
}

extern "C" void kernel_launch(void* const* d_in, const int* in_sizes, int n_in,
                              void* d_out, int out_size, void* d_ws, size_t ws_size,
                              hipStream_t stream) {
    const float* spec = (const float*)d_in[0];
    const float* uns  = (const float*)d_in[1];
    float* out = (float*)d_out;
    (void)in_sizes; (void)n_in; (void)d_ws; (void)ws_size; (void)out_size;

    dim3 grid(4096 / 4);   // one wave per row, 4 waves per block
    dim3 block(256);
    fse_kernel<<<grid, block, 0, stream>>>(spec, uns, out);
}